// Round 6
// baseline (405.346 us; speedup 1.0000x reference)
//
#include <hip/hip_runtime.h>

// LayerStacks round 6: two-phase split.
//  A (unsorted): per-lane-bucket W1 weights from LDS (R1's conflict-free slot
//    stride), natural-order coalesced-ish x stream with named-register
//    depth-2 prefetch, fused ply histogram. Writes l1[16]+accA+accP.
//  prep: scan (64-aligned bucket bases + pad fill) + scatter (perm).
//  B (sorted): wave-uniform bucket -> W2/Wout/b2/bout s_load'ed RAW from
//    global (full SGPR budget, no repack). Writes out.
//
// d_ws: ints [0..8) cnt, [8..16) cursor, [16..16+padcap) perm ((b<<26)|s, -1=pad)
//       floats [16+padcap ..) l1buf, 20 floats/sample (16B-aligned stride)

#define NB 6
#define STR 2340          // LDS slot stride (floats); 2340 % 32 == 4 -> 6 slots
                          // land on 6 distinct 16B bank-groups -> b128 conflict-free
#define O_W1T  0          // [c=0..31][j=0..7][q=0..3] c-major W1b quads
#define O_WPAT 1024       // same, W1pa
#define O_WOM  2048       // Wout[64..192)  (x_base partial dot)
#define O_WOH  2176       // Wout[192..320) (x_pa partial dot)
#define O_MISC 2304       // [0:8) W1b[:,128] [8:16) W1pa[:,128] [16:24) b1b [24:32) b1pa
#define SMASK  0x03FFFFFF

// ---------------- Kernel A: L1 + Wout partial dots + histogram ---------------
#define STEP_B(X, C) do {                                                      \
    const float* wc_ = wp + O_W1T + (C) * 32;                                  \
    _Pragma("unroll")                                                          \
    for (int j_ = 0; j_ < 8; ++j_) {                                           \
        const float4 w_ = *reinterpret_cast<const float4*>(wc_ + j_ * 4);      \
        acc1[j_] += w_.x*(X).x + w_.y*(X).y + w_.z*(X).z + w_.w*(X).w;         \
    }                                                                          \
    const float4 o_ = *reinterpret_cast<const float4*>(wp + O_WOM + (C) * 4);  \
    accA += o_.x*(X).x + o_.y*(X).y + o_.z*(X).z + o_.w*(X).w;                 \
} while (0)

#define STEP_P(X, C) do {                                                      \
    const float* wc_ = wp + O_WPAT + (C) * 32;                                 \
    _Pragma("unroll")                                                          \
    for (int j_ = 0; j_ < 8; ++j_) {                                           \
        const float4 w_ = *reinterpret_cast<const float4*>(wc_ + j_ * 4);      \
        acc1[8 + j_] += w_.x*(X).x + w_.y*(X).y + w_.z*(X).z + w_.w*(X).w;     \
    }                                                                          \
    const float4 o_ = *reinterpret_cast<const float4*>(wp + O_WOH + (C) * 4);  \
    accP += o_.x*(X).x + o_.y*(X).y + o_.z*(X).z + o_.w*(X).w;                 \
} while (0)

#define CHUNK_B(C0, X0, X1, X2, X3) do { STEP_B(X0, (C0)); STEP_B(X1, (C0)+1); \
    STEP_B(X2, (C0)+2); STEP_B(X3, (C0)+3); } while (0)
#define CHUNK_P(C0, X0, X1, X2, X3) do { STEP_P(X0, (C0)); STEP_P(X1, (C0)+1); \
    STEP_P(X2, (C0)+2); STEP_P(X3, (C0)+3); } while (0)

__global__ __launch_bounds__(1024, 4)
void layerstacks_l1(const float* __restrict__ x_base,
                    const float* __restrict__ x_pa,
                    const float* __restrict__ mobility,
                    const int*   __restrict__ ply,
                    const float* __restrict__ W1b,
                    const float* __restrict__ b1b,
                    const float* __restrict__ W1pa,
                    const float* __restrict__ b1pa,
                    const float* __restrict__ Wout,
                    int* __restrict__ cnt,          // global histogram [6]
                    float* __restrict__ l1buf, int B)
{
    __shared__ float lds[NB * STR];   // 54.9 KB
    __shared__ int lh[8];
    const int tid = threadIdx.x;
    if (tid < 8) lh[tid] = 0;

    // stage W1 c-major quads
    for (int e = tid; e < NB * 1024; e += 1024) {
        int b = e >> 10, r = e & 1023;
        int c = r >> 5, j = (r >> 2) & 7, q = r & 3;
        int src = b * 1032 + j * 129 + c * 4 + q;
        lds[b * STR + O_W1T + r]  = W1b[src];
        lds[b * STR + O_WPAT + r] = W1pa[src];
    }
    // Wout mid/high slices
    for (int e = tid; e < NB * 128; e += 1024) {
        int b = e >> 7, t = e & 127;
        lds[b * STR + O_WOM + t] = Wout[b * 320 + 64 + t];
        lds[b * STR + O_WOH + t] = Wout[b * 320 + 192 + t];
    }
    // misc: mobility cols + biases
    for (int e = tid; e < NB * 8; e += 1024) {
        int b = e >> 3, j = e & 7;
        lds[b * STR + O_MISC + 0  + j] = W1b [b * 1032 + j * 129 + 128];
        lds[b * STR + O_MISC + 8  + j] = W1pa[b * 1032 + j * 129 + 128];
        lds[b * STR + O_MISC + 16 + j] = b1b[e];
        lds[b * STR + O_MISC + 24 + j] = b1pa[e];
    }
    __syncthreads();

    const int s = blockIdx.x * 1024 + tid;           // grid exact: B/1024 blocks
    const int b = ply[s] / 10;
    atomicAdd(&lh[b], 1);
    const float* wp = lds + b * STR;                 // per-lane bucket slot

    const float mob = fminf(mobility[s] * (7.0f / 255.0f), 1.0f);

    float acc1[16];
    #pragma unroll
    for (int j = 0; j < 8; ++j)
        acc1[j]     = wp[O_MISC + 16 + j] + wp[O_MISC + 0 + j] * mob;
    #pragma unroll
    for (int j = 0; j < 8; ++j)
        acc1[8 + j] = wp[O_MISC + 24 + j] + wp[O_MISC + 8 + j] * mob;
    float accA = 0.0f, accP = 0.0f;

    const float4* __restrict__ xb4 = reinterpret_cast<const float4*>(x_base + (size_t)s * 128);
    const float4* __restrict__ xp4 = reinterpret_cast<const float4*>(x_pa   + (size_t)s * 128);

    // named-register depth-2 pipeline, 8 chunks x (4 base + 4 pa c-steps)
    float4 A0 = xb4[0],  A1 = xb4[1],  A2 = xb4[2],  A3 = xb4[3];
    float4 P0 = xp4[0],  P1 = xp4[1],  P2 = xp4[2],  P3 = xp4[3];
    float4 B0 = xb4[4],  B1 = xb4[5],  B2 = xb4[6],  B3 = xb4[7];
    float4 Q0 = xp4[4],  Q1 = xp4[5],  Q2 = xp4[6],  Q3 = xp4[7];

    CHUNK_B(0,  A0, A1, A2, A3);  CHUNK_P(0,  P0, P1, P2, P3);
    A0 = xb4[8];  A1 = xb4[9];  A2 = xb4[10]; A3 = xb4[11];
    P0 = xp4[8];  P1 = xp4[9];  P2 = xp4[10]; P3 = xp4[11];
    CHUNK_B(4,  B0, B1, B2, B3);  CHUNK_P(4,  Q0, Q1, Q2, Q3);
    B0 = xb4[12]; B1 = xb4[13]; B2 = xb4[14]; B3 = xb4[15];
    Q0 = xp4[12]; Q1 = xp4[13]; Q2 = xp4[14]; Q3 = xp4[15];
    CHUNK_B(8,  A0, A1, A2, A3);  CHUNK_P(8,  P0, P1, P2, P3);
    A0 = xb4[16]; A1 = xb4[17]; A2 = xb4[18]; A3 = xb4[19];
    P0 = xp4[16]; P1 = xp4[17]; P2 = xp4[18]; P3 = xp4[19];
    CHUNK_B(12, B0, B1, B2, B3);  CHUNK_P(12, Q0, Q1, Q2, Q3);
    B0 = xb4[20]; B1 = xb4[21]; B2 = xb4[22]; B3 = xb4[23];
    Q0 = xp4[20]; Q1 = xp4[21]; Q2 = xp4[22]; Q3 = xp4[23];
    CHUNK_B(16, A0, A1, A2, A3);  CHUNK_P(16, P0, P1, P2, P3);
    A0 = xb4[24]; A1 = xb4[25]; A2 = xb4[26]; A3 = xb4[27];
    P0 = xp4[24]; P1 = xp4[25]; P2 = xp4[26]; P3 = xp4[27];
    CHUNK_B(20, B0, B1, B2, B3);  CHUNK_P(20, Q0, Q1, Q2, Q3);
    B0 = xb4[28]; B1 = xb4[29]; B2 = xb4[30]; B3 = xb4[31];
    Q0 = xp4[28]; Q1 = xp4[29]; Q2 = xp4[30]; Q3 = xp4[31];
    CHUNK_B(24, A0, A1, A2, A3);  CHUNK_P(24, P0, P1, P2, P3);
    CHUNK_B(28, B0, B1, B2, B3);  CHUNK_P(28, Q0, Q1, Q2, Q3);

    float* op = l1buf + (size_t)s * 20;
    *reinterpret_cast<float4*>(op + 0)  = make_float4(acc1[0],  acc1[1],  acc1[2],  acc1[3]);
    *reinterpret_cast<float4*>(op + 4)  = make_float4(acc1[4],  acc1[5],  acc1[6],  acc1[7]);
    *reinterpret_cast<float4*>(op + 8)  = make_float4(acc1[8],  acc1[9],  acc1[10], acc1[11]);
    *reinterpret_cast<float4*>(op + 12) = make_float4(acc1[12], acc1[13], acc1[14], acc1[15]);
    *reinterpret_cast<float2*>(op + 16) = make_float2(accA, accP);

    __syncthreads();
    if (tid < NB) atomicAdd(&cnt[tid], lh[tid]);
}

// ---------------- scan: 64-aligned bases + pad fill --------------------------
__global__ void k_scan(int* __restrict__ wsI, int B) {
    if (threadIdx.x != 0) return;
    int* perm = wsI + 16;
    const int padcap = B + NB * 64;
    int base = 0;
    for (int b = 0; b < NB; ++b) {
        wsI[8 + b] = base;
        const int cnt = wsI[b];
        const int end = base + cnt;
        const int cend = base + ((cnt + 63) & ~63);
        for (int i = end; i < cend; ++i) perm[i] = -1;
        base = cend;
    }
    for (int i = base; i < padcap; ++i) perm[i] = -1;
}

// ---------------- scatter: perm = (b<<26)|s ----------------------------------
__global__ __launch_bounds__(1024)
void k_scatter(const int* __restrict__ ply, int* __restrict__ wsI, int B) {
    __shared__ int lh[NB];
    __shared__ int lbase[NB];
    int* cursor = wsI + 8;
    int* perm   = wsI + 16;
    const int tid = threadIdx.x;
    if (tid < NB) lh[tid] = 0;
    __syncthreads();
    const int s = blockIdx.x * 1024 + tid;
    int b = 0, lpos = 0;
    if (s < B) { b = ply[s] / 10; lpos = atomicAdd(&lh[b], 1); }
    __syncthreads();
    if (tid < NB) lbase[tid] = atomicAdd(&cursor[tid], lh[tid]);
    __syncthreads();
    if (s < B) perm[lbase[b] + lpos] = s | (b << 26);
}

// ---------------- Kernel B: L2 + output (sorted, scalar weights) -------------
__global__ __launch_bounds__(256, 4)
void layerstacks_l2(const float* __restrict__ l1buf,
                    const int*   __restrict__ wsI,
                    const float* __restrict__ W2,
                    const float* __restrict__ b2,
                    const float* __restrict__ Wout,
                    const float* __restrict__ bout,
                    float* __restrict__ out, int B, int padcap)
{
    const int pos = blockIdx.x * 256 + threadIdx.x;
    const int* perm = wsI + 16;
    int e = (pos < padcap) ? perm[pos] : -1;
    const int e0 = __builtin_amdgcn_readfirstlane(e);
    if (e0 < 0) return;                              // whole wave padding

    const int bu = e0 >> 26;                         // wave-uniform (SGPR)
    const bool valid = (e >= 0);
    const int s  = e & SMASK;
    const int su = valid ? s : (e0 & SMASK);

    const float* lp = l1buf + (size_t)su * 20;
    const float4 v0 = *reinterpret_cast<const float4*>(lp + 0);
    const float4 v1 = *reinterpret_cast<const float4*>(lp + 4);
    const float4 v2 = *reinterpret_cast<const float4*>(lp + 8);
    const float4 v3 = *reinterpret_cast<const float4*>(lp + 12);
    const float2 v4 = *reinterpret_cast<const float2*>(lp + 16);

    float l1[16] = { v0.x, v0.y, v0.z, v0.w, v1.x, v1.y, v1.z, v1.w,
                     v2.x, v2.y, v2.z, v2.w, v3.x, v3.y, v3.z, v3.w };
    float l1c[32];
    #pragma unroll
    for (int k = 0; k < 16; ++k) {
        const float v = l1[k];
        l1c[16 + k] = fminf(fmaxf(v, 0.0f), 1.0f);
        l1c[k] = fminf(v * v * (255.0f / 256.0f), 1.0f);
    }

    const float* __restrict__ W2b = W2   + bu * 2048;
    const float* __restrict__ Wob = Wout + bu * 320;
    const float* __restrict__ b2b = b2   + bu * 64;

    float accL = 0.0f;
    #pragma unroll 4
    for (int j = 0; j < 64; ++j) {
        float a = b2b[j];
        #pragma unroll
        for (int kq = 0; kq < 8; ++kq) {
            const float4 w = *reinterpret_cast<const float4*>(W2b + j * 32 + kq * 4);
            a += w.x * l1c[kq * 4] + w.y * l1c[kq * 4 + 1]
               + w.z * l1c[kq * 4 + 2] + w.w * l1c[kq * 4 + 3];
        }
        a = fminf(fmaxf(a, 0.0f), 1.0f);
        a = a * a * (255.0f / 256.0f);
        accL += Wob[j] * a;
    }

    if (valid) out[s] = bout[bu] + v4.x + v4.y + accL;
}

// ---------------- fallback: round-1 kernel (93.7 us) -------------------------
#define FB_BSTR 4580
#define FO_W1B  0
#define FO_W1PA 1056
#define FO_W2   2112
#define FO_WOUT 4160
#define FO_B1B  4480
#define FO_B1PA 4488
#define FO_B2   4496
#define FO_BOUT 4560

__global__ __launch_bounds__(1024, 1)
void layerstacks_fallback(const float* __restrict__ x_base,
                          const float* __restrict__ x_pa,
                          const float* __restrict__ mobility,
                          const int*   __restrict__ ply,
                          const float* __restrict__ W1b,
                          const float* __restrict__ b1b,
                          const float* __restrict__ W1pa,
                          const float* __restrict__ b1pa,
                          const float* __restrict__ W2,
                          const float* __restrict__ b2,
                          const float* __restrict__ Wout,
                          const float* __restrict__ bout,
                          float* __restrict__ out)
{
    __shared__ float lds[NB * FB_BSTR];
    const int tid = threadIdx.x;
    for (int e = tid; e < NB * 1032; e += 1024) {
        int b = e / 1032, r = e - b * 1032;
        int row = r / 129, col = r - row * 129;
        lds[b * FB_BSTR + FO_W1B + row * 132 + col] = W1b[e];
        lds[b * FB_BSTR + FO_W1PA + row * 132 + col] = W1pa[e];
    }
    for (int e = tid; e < NB * 2048; e += 1024) {
        int b = e >> 11, r = e & 2047;
        lds[b * FB_BSTR + FO_W2 + r] = W2[e];
    }
    for (int e = tid; e < NB * 320; e += 1024) {
        int b = e / 320, r = e - b * 320;
        lds[b * FB_BSTR + FO_WOUT + r] = Wout[e];
    }
    if (tid < NB * 8) {
        int b = tid >> 3, r = tid & 7;
        lds[b * FB_BSTR + FO_B1B + r]  = b1b[tid];
        lds[b * FB_BSTR + FO_B1PA + r] = b1pa[tid];
    }
    for (int e = tid; e < NB * 64; e += 1024) {
        int b = e >> 6, r = e & 63;
        lds[b * FB_BSTR + FO_B2 + r] = b2[e];
    }
    if (tid < NB) lds[tid * FB_BSTR + FO_BOUT] = bout[tid];
    __syncthreads();

    const int s = blockIdx.x * 1024 + tid;
    const int idx = ply[s] / 10;
    const float* bk = &lds[idx * FB_BSTR];
    const float mob = fminf(mobility[s] * (7.0f / 255.0f), 1.0f);

    float acc1[16];
    #pragma unroll
    for (int j = 0; j < 8; ++j)
        acc1[j] = bk[FO_B1B + j] + bk[FO_W1B + j * 132 + 128] * mob;
    #pragma unroll
    for (int j = 0; j < 8; ++j)
        acc1[8 + j] = bk[FO_B1PA + j] + bk[FO_W1PA + j * 132 + 128] * mob;
    float accout = bk[FO_BOUT];

    const float4* xb4 = reinterpret_cast<const float4*>(x_base + (size_t)s * 128);
    const float4* xp4 = reinterpret_cast<const float4*>(x_pa   + (size_t)s * 128);
    #pragma unroll 4
    for (int c = 0; c < 32; ++c) {
        const float4 x = xb4[c];
        #pragma unroll
        for (int j = 0; j < 8; ++j) {
            const float4 w = *reinterpret_cast<const float4*>(&bk[FO_W1B + j * 132 + c * 4]);
            acc1[j] += w.x * x.x + w.y * x.y + w.z * x.z + w.w * x.w;
        }
        const float4 wo = *reinterpret_cast<const float4*>(&bk[FO_WOUT + 64 + c * 4]);
        accout += wo.x * x.x + wo.y * x.y + wo.z * x.z + wo.w * x.w;
    }
    #pragma unroll 4
    for (int c = 0; c < 32; ++c) {
        const float4 x = xp4[c];
        #pragma unroll
        for (int j = 0; j < 8; ++j) {
            const float4 w = *reinterpret_cast<const float4*>(&bk[FO_W1PA + j * 132 + c * 4]);
            acc1[8 + j] += w.x * x.x + w.y * x.y + w.z * x.z + w.w * x.w;
        }
        const float4 wo = *reinterpret_cast<const float4*>(&bk[FO_WOUT + 192 + c * 4]);
        accout += wo.x * x.x + wo.y * x.y + wo.z * x.z + wo.w * x.w;
    }
    float l1c[32];
    #pragma unroll
    for (int k = 0; k < 16; ++k) {
        const float v = acc1[k];
        l1c[16 + k] = fminf(fmaxf(v, 0.0f), 1.0f);
        l1c[k] = fminf(v * v * (255.0f / 256.0f), 1.0f);
    }
    #pragma unroll 4
    for (int j = 0; j < 64; ++j) {
        float a = bk[FO_B2 + j];
        #pragma unroll
        for (int k = 0; k < 32; k += 4) {
            const float4 w = *reinterpret_cast<const float4*>(&bk[FO_W2 + j * 32 + k]);
            a += w.x * l1c[k] + w.y * l1c[k + 1] + w.z * l1c[k + 2] + w.w * l1c[k + 3];
        }
        a = fminf(fmaxf(a, 0.0f), 1.0f);
        a = a * a * (255.0f / 256.0f);
        accout += bk[FO_WOUT + j] * a;
    }
    out[s] = accout;
}

extern "C" void kernel_launch(void* const* d_in, const int* in_sizes, int n_in,
                              void* d_out, int out_size, void* d_ws, size_t ws_size,
                              hipStream_t stream) {
    const float* x_base   = (const float*)d_in[0];
    const float* x_pa     = (const float*)d_in[1];
    const float* mobility = (const float*)d_in[2];
    const int*   ply      = (const int*)d_in[3];
    const float* W1b      = (const float*)d_in[4];
    const float* b1b      = (const float*)d_in[5];
    const float* W1pa     = (const float*)d_in[6];
    const float* b1pa     = (const float*)d_in[7];
    const float* W2       = (const float*)d_in[8];
    const float* b2       = (const float*)d_in[9];
    const float* Wout     = (const float*)d_in[10];
    const float* bout     = (const float*)d_in[11];
    float* out = (float*)d_out;

    const int B = in_sizes[3];                       // 262144
    const int padcap = B + NB * 64;                  // 262528
    const size_t ws_needed = (size_t)(16 + padcap) * 4 + (size_t)B * 20 * 4;

    if (ws_size >= ws_needed) {
        int*   wsI   = (int*)d_ws;
        float* l1buf = (float*)d_ws + 16 + padcap;

        hipMemsetAsync(wsI, 0, 16 * sizeof(int), stream);
        layerstacks_l1<<<B / 1024, 1024, 0, stream>>>(
            x_base, x_pa, mobility, ply, W1b, b1b, W1pa, b1pa, Wout,
            wsI, l1buf, B);
        k_scan<<<1, 64, 0, stream>>>(wsI, B);
        k_scatter<<<(B + 1023) / 1024, 1024, 0, stream>>>(ply, wsI, B);
        layerstacks_l2<<<(padcap + 255) / 256, 256, 0, stream>>>(
            l1buf, wsI, W2, b2, Wout, bout, out, B, padcap);
    } else {
        layerstacks_fallback<<<B / 1024, 1024, 0, stream>>>(
            x_base, x_pa, mobility, ply, W1b, b1b, W1pa, b1pa, W2, b2, Wout, bout, out);
    }
}

// Round 7
// 76.373 us; speedup vs baseline: 5.3074x; 5.3074x over previous
//
#include <hip/hip_runtime.h>

// LayerStacks round 7: R1 structure (single kernel, no sort, per-lane bucket
// weights in LDS) with ALL weights stored as f16 and dot-products done via
// v_dot2_f32_f16 (__builtin_amdgcn_fdot2). Halves the LDS byte stream, which
// round-1 counters showed to be the binding pipe (~88 us floor at f32).
//
// Bucket slot byte-stride SLOT % 128 == 16 -> the 6 buckets' identical-offset
// reads land on 6 disjoint 16B bank groups -> conflict-free multi-broadcast
// (verified by R1's near-zero SQ_LDS_BANK_CONFLICT with the same trick).

#define NB 6
// byte offsets inside one bucket slot
#define S_W1T   0      // f16[1024]: [cg0..31][j0..7][q0..3] c-major W1b quads
#define S_WPAT  2048   // f16[1024]: same for W1pa
#define S_W2    4096   // f16[2048]: [j0..63][k0..31] row-major
#define S_WOM   8192   // f16[128]:  Wout[64..192)
#define S_WOH   8448   // f16[128]:  Wout[192..320)
#define S_WO0   8704   // f16[64]:   Wout[0..64)
#define S_B1B   8832   // f32[8]
#define S_B1PA  8864   // f32[8]
#define S_MW1B  8896   // f32[8]  W1b[:,128]  (mobility col, kept f32)
#define S_MW1PA 8928   // f32[8]
#define S_B2    8960   // f32[64]
#define S_BOUT  9216   // f32[1]
#define SLOT    9232   // 9232 % 128 == 16

typedef __fp16 h2 __attribute__((ext_vector_type(2)));
typedef __fp16 h4 __attribute__((ext_vector_type(4)));
typedef __fp16 h8 __attribute__((ext_vector_type(8)));

#define SH(v, a, b) __builtin_shufflevector((v), (v), (a), (b))

__device__ __forceinline__ float fdot2f(h2 a, h2 b, float c) {
#if __has_builtin(__builtin_amdgcn_fdot2)
    return __builtin_amdgcn_fdot2(a, b, c, false);
#else
    return (float)a[0] * (float)b[0] + (float)a[1] * (float)b[1] + c;
#endif
}

__device__ __forceinline__ h2 pk2(float x, float y) {
#if __has_builtin(__builtin_amdgcn_cvt_pkrtz)
    return __builtin_bit_cast(h2, __builtin_amdgcn_cvt_pkrtz(x, y));
#else
    h2 r; r[0] = (__fp16)x; r[1] = (__fp16)y; return r;
#endif
}

__global__ __launch_bounds__(1024)
void layerstacks_f16(const float* __restrict__ x_base,
                     const float* __restrict__ x_pa,
                     const float* __restrict__ mobility,
                     const int*   __restrict__ ply,
                     const float* __restrict__ W1b,
                     const float* __restrict__ b1b,
                     const float* __restrict__ W1pa,
                     const float* __restrict__ b1pa,
                     const float* __restrict__ W2,
                     const float* __restrict__ b2,
                     const float* __restrict__ Wout,
                     const float* __restrict__ bout,
                     float* __restrict__ out, int B)
{
    __shared__ __align__(16) char lds[NB * SLOT];   // 55392 B
    const int tid = threadIdx.x;

    // ---------------- stage weights into LDS (f32 -> f16) -------------------
    for (int e = tid; e < NB * 1024; e += 1024) {
        int b = e >> 10, r = e & 1023;
        int cg = r >> 5, j = (r >> 2) & 7, q = r & 3;
        int src = b * 1032 + j * 129 + cg * 4 + q;
        *(__fp16*)(lds + b * SLOT + S_W1T  + r * 2) = (__fp16)W1b[src];
        *(__fp16*)(lds + b * SLOT + S_WPAT + r * 2) = (__fp16)W1pa[src];
    }
    for (int e = tid; e < NB * 2048; e += 1024) {
        int b = e >> 11, r = e & 2047;
        *(__fp16*)(lds + b * SLOT + S_W2 + r * 2) = (__fp16)W2[e];
    }
    for (int e = tid; e < NB * 128; e += 1024) {
        int b = e >> 7, t = e & 127;
        *(__fp16*)(lds + b * SLOT + S_WOM + t * 2) = (__fp16)Wout[b * 320 + 64 + t];
        *(__fp16*)(lds + b * SLOT + S_WOH + t * 2) = (__fp16)Wout[b * 320 + 192 + t];
    }
    for (int e = tid; e < NB * 64; e += 1024) {
        int b = e >> 6, t = e & 63;
        *(__fp16*)(lds + b * SLOT + S_WO0 + t * 2) = (__fp16)Wout[b * 320 + t];
        *(float*)(lds + b * SLOT + S_B2 + t * 4) = b2[e];
    }
    if (tid < NB * 8) {
        int b = tid >> 3, j = tid & 7;
        *(float*)(lds + b * SLOT + S_B1B   + j * 4) = b1b[tid];
        *(float*)(lds + b * SLOT + S_B1PA  + j * 4) = b1pa[tid];
        *(float*)(lds + b * SLOT + S_MW1B  + j * 4) = W1b [b * 1032 + j * 129 + 128];
        *(float*)(lds + b * SLOT + S_MW1PA + j * 4) = W1pa[b * 1032 + j * 129 + 128];
    }
    if (tid < NB) *(float*)(lds + tid * SLOT + S_BOUT) = bout[tid];
    __syncthreads();

    // ---------------- per-sample compute ------------------------------------
    const int s = blockIdx.x * 1024 + tid;
    if (s >= B) return;
    const char* __restrict__ wp = lds + (ply[s] / 10) * SLOT;
    const float mob = fminf(mobility[s] * (7.0f / 255.0f), 1.0f);

    float acc1[16];
    #pragma unroll
    for (int j = 0; j < 8; ++j)
        acc1[j] = *(const float*)(wp + S_B1B + j * 4)
                + *(const float*)(wp + S_MW1B + j * 4) * mob;
    #pragma unroll
    for (int j = 0; j < 8; ++j)
        acc1[8 + j] = *(const float*)(wp + S_B1PA + j * 4)
                    + *(const float*)(wp + S_MW1PA + j * 4) * mob;

    float accA = 0.0f, accP = 0.0f;
    const float4* __restrict__ xb4 = (const float4*)(x_base + (size_t)s * 128);
    const float4* __restrict__ xp4 = (const float4*)(x_pa   + (size_t)s * 128);

    // ---- x_base stream: L1-base rows + Wout[64:192) dot --------------------
    #pragma unroll 4
    for (int cg = 0; cg < 32; ++cg) {
        const float4 x = xb4[cg];
        const h2 x01 = pk2(x.x, x.y);
        const h2 x23 = pk2(x.z, x.w);
        #pragma unroll
        for (int jp = 0; jp < 4; ++jp) {
            const h8 w = *(const h8*)(wp + S_W1T + cg * 64 + jp * 16);
            acc1[2*jp]   = fdot2f(x23, SH(w,2,3), fdot2f(x01, SH(w,0,1), acc1[2*jp]));
            acc1[2*jp+1] = fdot2f(x23, SH(w,6,7), fdot2f(x01, SH(w,4,5), acc1[2*jp+1]));
        }
        const h4 wo = *(const h4*)(wp + S_WOM + cg * 8);
        accA = fdot2f(x23, SH(wo,2,3), fdot2f(x01, SH(wo,0,1), accA));
    }
    // ---- x_pa stream: L1-pa rows + Wout[192:320) dot -----------------------
    #pragma unroll 4
    for (int cg = 0; cg < 32; ++cg) {
        const float4 x = xp4[cg];
        const h2 x01 = pk2(x.x, x.y);
        const h2 x23 = pk2(x.z, x.w);
        #pragma unroll
        for (int jp = 0; jp < 4; ++jp) {
            const h8 w = *(const h8*)(wp + S_WPAT + cg * 64 + jp * 16);
            acc1[8+2*jp]   = fdot2f(x23, SH(w,2,3), fdot2f(x01, SH(w,0,1), acc1[8+2*jp]));
            acc1[8+2*jp+1] = fdot2f(x23, SH(w,6,7), fdot2f(x01, SH(w,4,5), acc1[8+2*jp+1]));
        }
        const h4 wo = *(const h4*)(wp + S_WOH + cg * 8);
        accP = fdot2f(x23, SH(wo,2,3), fdot2f(x01, SH(wo,0,1), accP));
    }

    // ---- l1c packed to f16 pairs: [sq(0..15) | lin(0..15)] -----------------
    h2 p2[16];
    #pragma unroll
    for (int k = 0; k < 8; ++k) {
        const float v0 = acc1[2*k], v1 = acc1[2*k+1];
        p2[k] = pk2(fminf(v0 * v0 * (255.0f / 256.0f), 1.0f),
                    fminf(v1 * v1 * (255.0f / 256.0f), 1.0f));
        p2[8 + k] = pk2(fminf(fmaxf(v0, 0.0f), 1.0f),
                        fminf(fmaxf(v1, 0.0f), 1.0f));
    }

    // ---- L2 (64x32) + Wout[0:64) dot ---------------------------------------
    float accL = 0.0f;
    #pragma unroll 4
    for (int j = 0; j < 64; ++j) {
        const char* rp = wp + S_W2 + j * 64;
        const h8 wa = *(const h8*)(rp);
        const h8 wb = *(const h8*)(rp + 16);
        const h8 wc = *(const h8*)(rp + 32);
        const h8 wd = *(const h8*)(rp + 48);
        float a = *(const float*)(wp + S_B2 + j * 4);
        a = fdot2f(p2[0],  SH(wa,0,1), a);
        a = fdot2f(p2[1],  SH(wa,2,3), a);
        a = fdot2f(p2[2],  SH(wa,4,5), a);
        a = fdot2f(p2[3],  SH(wa,6,7), a);
        a = fdot2f(p2[4],  SH(wb,0,1), a);
        a = fdot2f(p2[5],  SH(wb,2,3), a);
        a = fdot2f(p2[6],  SH(wb,4,5), a);
        a = fdot2f(p2[7],  SH(wb,6,7), a);
        a = fdot2f(p2[8],  SH(wc,0,1), a);
        a = fdot2f(p2[9],  SH(wc,2,3), a);
        a = fdot2f(p2[10], SH(wc,4,5), a);
        a = fdot2f(p2[11], SH(wc,6,7), a);
        a = fdot2f(p2[12], SH(wd,0,1), a);
        a = fdot2f(p2[13], SH(wd,2,3), a);
        a = fdot2f(p2[14], SH(wd,4,5), a);
        a = fdot2f(p2[15], SH(wd,6,7), a);
        a = fminf(fmaxf(a, 0.0f), 1.0f);
        a = a * a * (255.0f / 256.0f);
        accL += (float)(*(const __fp16*)(wp + S_WO0 + j * 2)) * a;
    }

    out[s] = *(const float*)(wp + S_BOUT) + accA + accP + accL;
}

extern "C" void kernel_launch(void* const* d_in, const int* in_sizes, int n_in,
                              void* d_out, int out_size, void* d_ws, size_t ws_size,
                              hipStream_t stream) {
    const float* x_base   = (const float*)d_in[0];
    const float* x_pa     = (const float*)d_in[1];
    const float* mobility = (const float*)d_in[2];
    const int*   ply      = (const int*)d_in[3];
    const float* W1b      = (const float*)d_in[4];
    const float* b1b      = (const float*)d_in[5];
    const float* W1pa     = (const float*)d_in[6];
    const float* b1pa     = (const float*)d_in[7];
    const float* W2       = (const float*)d_in[8];
    const float* b2       = (const float*)d_in[9];
    const float* Wout     = (const float*)d_in[10];
    const float* bout     = (const float*)d_in[11];
    float* out = (float*)d_out;

    const int B = in_sizes[3];                 // 262144
    const int blocks = (B + 1023) / 1024;      // 256
    layerstacks_f16<<<blocks, 1024, 0, stream>>>(
        x_base, x_pa, mobility, ply, W1b, b1b, W1pa, b1pa, W2, b2, Wout, bout,
        out, B);
}

// Round 8
// 63.283 us; speedup vs baseline: 6.4053x; 1.2069x over previous
//
#include <hip/hip_runtime.h>

// LayerStacks round 8: MFMA (16x16x32 f16) with in-block bucket grouping.
// Block = 1024 threads = 16 waves, processes 1024 consecutive samples.
// Phase 0: stage all 6 buckets' weights into LDS in MFMA fragment layouts
//          (f16), group samples into per-bucket lists (padded to x16).
// Main:    each wave processes 16-sample tiles (bucket-uniform):
//          stage1: two 16x16 MFMA chains over K=128 (x_base->W1b|WoutM,
//                  x_pa->W1pa|WoutH), cols 0..7 = l1 rows, col 8 = Wout dot.
//          l1c transpose via per-wave LDS scratch (80B stride, f16 pairs).
//          stage2: 4 MFMAs (K=32) -> L2 neurons, activation, Wout[0:64] dot,
//          16-lane shfl reduce, store.
// Fragment convention (verified C/D layout m89/m91 + attention operand note):
//   A/B operand: lane&15 = output-facing index (m for A, n for B),
//                k = (lane>>4)*8 + i;  D: col=lane&15 (n), row=(lane>>4)*4+reg.

#define NB 6

typedef _Float16 h2 __attribute__((ext_vector_type(2)));
typedef _Float16 h8 __attribute__((ext_vector_type(8)));
typedef float f4 __attribute__((ext_vector_type(4)));

__device__ __forceinline__ h2 pk2(float x, float y) {
    return __builtin_bit_cast(h2, __builtin_amdgcn_cvt_pkrtz(x, y));
}

__device__ __forceinline__ h8 pack8(const float4 a, const float4 b) {
    h2 p0 = pk2(a.x, a.y), p1 = pk2(a.z, a.w);
    h2 p2 = pk2(b.x, b.y), p3 = pk2(b.z, b.w);
    h8 r;
    r[0] = p0[0]; r[1] = p0[1]; r[2] = p1[0]; r[3] = p1[1];
    r[4] = p2[0]; r[5] = p2[1]; r[6] = p3[0]; r[7] = p3[1];
    return r;
}

__device__ __forceinline__ float actv(float v) {
    float u = fminf(fmaxf(v, 0.0f), 1.0f);
    return u * u * (255.0f / 256.0f);
}

__global__ __launch_bounds__(1024, 1)
void layerstacks_mfma(const float* __restrict__ x_base,
                      const float* __restrict__ x_pa,
                      const float* __restrict__ mobility,
                      const int*   __restrict__ ply,
                      const float* __restrict__ W1b,
                      const float* __restrict__ b1b,
                      const float* __restrict__ W1pa,
                      const float* __restrict__ b1pa,
                      const float* __restrict__ W2,
                      const float* __restrict__ b2,
                      const float* __restrict__ Wout,
                      const float* __restrict__ bout,
                      float* __restrict__ out)
{
    // ---- LDS (≈85.5 KB total) ----
    __shared__ __align__(16) _Float16 sW1[NB][2][4][4][9][8]; // [b][st][t][kb][n<=8][i] 27.6KB
    __shared__ __align__(16) _Float16 sW2[NB][4][4][16][8];   // [b][T][kb][j][i]       24.6KB
    __shared__ float sWo0[NB][64];   // Wout[0:64)
    __shared__ float sB2[NB][64];    // b2
    __shared__ float sB1[NB][4][8];  // {b1b,b1pa,mw1b,mw1pa}
    __shared__ float sBout[NB];
    __shared__ float sMob[1024];
    __shared__ int   sList[1120];
    __shared__ __align__(16) char sL1[16 * 1280]; // per-wave scratch: 16 rows x 80B
    __shared__ int sCnt[8], sCur[8], sTb[72];
    __shared__ int sNt;

    const int tid   = threadIdx.x;
    const int lane  = tid & 63;
    const int w     = tid >> 6;
    const int gbase = blockIdx.x << 10;

    // ---------------- phase 0: staging --------------------------------------
    if (tid < 8) { sCnt[tid] = 0; }

    // W1 fragments: value = n<8 ? W1x[n][k] : WoutSlice[k]; k = t*32+kb*8+i
    for (int e = tid; e < NB * 2 * 4 * 4 * 9 * 8; e += 1024) {
        int i = e & 7;
        int rest = e >> 3;
        int n = rest % 9;   rest /= 9;
        int kb = rest & 3;  rest >>= 2;
        int t = rest & 3;   rest >>= 2;
        int st = rest & 1;
        int b = rest >> 1;
        int k = t * 32 + kb * 8 + i;
        float v;
        if (n < 8) {
            const float* Wx = st ? W1pa : W1b;
            v = Wx[b * 1032 + n * 129 + k];
        } else {
            v = st ? Wout[b * 320 + 192 + k] : Wout[b * 320 + 64 + k];
        }
        sW1[b][st][t][kb][n][i] = (_Float16)v;
    }
    // W2 fragments with (sq,lin)-interleaved feature order:
    // feature 2u -> W2 col u (sq), feature 2u+1 -> W2 col 16+u (lin)
    for (int e = tid; e < NB * 4 * 4 * 16 * 8; e += 1024) {
        int i = e & 7;
        int j = (e >> 3) & 15;
        int kb = (e >> 7) & 3;
        int T = (e >> 9) & 3;
        int b = e >> 11;
        int n = T * 16 + j;
        int k = kb * 8 + i;
        int u = k >> 1;
        int colw = (k & 1) ? (16 + u) : u;
        sW2[b][T][kb][j][i] = (_Float16)W2[b * 2048 + n * 32 + colw];
    }
    for (int e = tid; e < NB * 64; e += 1024) {
        int b = e >> 6, n = e & 63;
        sWo0[b][n] = Wout[b * 320 + n];
        sB2[b][n]  = b2[e];
    }
    if (tid < NB * 4 * 8) {
        int n = tid & 7, which = (tid >> 3) & 3, b = tid >> 5;
        float v;
        if (which == 0)      v = b1b[b * 8 + n];
        else if (which == 1) v = b1pa[b * 8 + n];
        else if (which == 2) v = W1b [b * 1032 + n * 129 + 128];
        else                 v = W1pa[b * 1032 + n * 129 + 128];
        sB1[b][which][n] = v;
    }
    if (tid < NB) sBout[tid] = bout[tid];
    sMob[tid] = fminf(mobility[gbase + tid] * (7.0f / 255.0f), 1.0f);
    for (int e = tid; e < 1120; e += 1024) sList[e] = -1;

    const int bb = ply[gbase + tid] / 10;
    __syncthreads();

    // ---------------- phase 1: ballot-aggregated counts ---------------------
    #pragma unroll
    for (int b = 0; b < NB; ++b) {
        unsigned long long mk = __ballot(bb == b);
        if (bb == b) {
            int lead = __ffsll((long long)mk) - 1;
            if (lane == lead) atomicAdd(&sCnt[b], __popcll(mk));
        }
    }
    __syncthreads();

    // ---------------- phase 2: offsets + tile->bucket map (serial) ----------
    if (tid == 0) {
        int off = 0, tt = 0;
        for (int b = 0; b < NB; ++b) {
            sCur[b] = off;
            int ntl = (sCnt[b] + 15) >> 4;
            for (int q = 0; q < ntl; ++q) sTb[tt++] = b;
            off += ntl << 4;
        }
        sNt = tt;
    }
    __syncthreads();

    // ---------------- phase 3: scatter local indices ------------------------
    #pragma unroll
    for (int b = 0; b < NB; ++b) {
        unsigned long long mk = __ballot(bb == b);
        if (bb == b) {
            int lead = __ffsll((long long)mk) - 1;
            int pfx = __popcll(mk & ((1ull << lane) - 1ull));
            int base = 0;
            if (lane == lead) base = atomicAdd(&sCur[b], __popcll(mk));
            base = __shfl(base, lead);
            sList[base + pfx] = tid;
        }
    }
    __syncthreads();

    // ---------------- main: per-wave MFMA tiles -----------------------------
    const int ntiles = sNt;
    const int col = lane & 15;   // n-index (neuron) for B/C, m-index for A
    const int qd  = lane >> 4;   // k-quarter / C row-group
    char* lb = sL1 + w * 1280;

    for (int tl = w; tl < ntiles; tl += 16) {
        const int bkt = sTb[tl];
        const int t16 = tl << 4;

        // C-row samples (rows qd*4+r) and A-row sample (row col)
        const int sl0 = sList[t16 + qd * 4 + 0];
        const int sl1 = sList[t16 + qd * 4 + 1];
        const int sl2 = sList[t16 + qd * 4 + 2];
        const int sl3 = sList[t16 + qd * 4 + 3];
        const float mob0 = (sl0 >= 0) ? sMob[sl0 & 1023] : 0.0f;
        const float mob1 = (sl1 >= 0) ? sMob[sl1 & 1023] : 0.0f;
        const float mob2 = (sl2 >= 0) ? sMob[sl2 & 1023] : 0.0f;
        const float mob3 = (sl3 >= 0) ? sMob[sl3 & 1023] : 0.0f;
        int sA = sList[t16 + col];
        if (sA < 0) sA = sList[t16];           // first entry of a tile is valid

        // ---- stage 1 seeds: cols<8 = b1 + mw*mob, col 8 (Wout dot) = 0 ----
        const int c7 = col & 7;
        const bool a8 = (col < 8);
        const float bb1 = sB1[bkt][0][c7], bp1 = sB1[bkt][1][c7];
        const float mwb = sB1[bkt][2][c7], mwp = sB1[bkt][3][c7];
        f4 cb, cp;
        cb[0] = a8 ? bb1 + mwb * mob0 : 0.0f;
        cb[1] = a8 ? bb1 + mwb * mob1 : 0.0f;
        cb[2] = a8 ? bb1 + mwb * mob2 : 0.0f;
        cb[3] = a8 ? bb1 + mwb * mob3 : 0.0f;
        cp[0] = a8 ? bp1 + mwp * mob0 : 0.0f;
        cp[1] = a8 ? bp1 + mwp * mob1 : 0.0f;
        cp[2] = a8 ? bp1 + mwp * mob2 : 0.0f;
        cp[3] = a8 ? bp1 + mwp * mob3 : 0.0f;

        const int ncl = a8 ? col : 8;
        const float* xbrow = x_base + (size_t)(gbase + sA) * 128;
        const float* xprow = x_pa   + (size_t)(gbase + sA) * 128;

        // ---- stage 1: K=128 in 4 MFMA steps per stream ----
        #pragma unroll
        for (int t4 = 0; t4 < 4; ++t4) {
            const float4 a0 = *(const float4*)(xbrow + t4 * 32 + qd * 8);
            const float4 a1 = *(const float4*)(xbrow + t4 * 32 + qd * 8 + 4);
            const float4 p0 = *(const float4*)(xprow + t4 * 32 + qd * 8);
            const float4 p1 = *(const float4*)(xprow + t4 * 32 + qd * 8 + 4);
            const h8 xa = pack8(a0, a1);
            const h8 xp = pack8(p0, p1);
            const h8 wa = *(const h8*)&sW1[bkt][0][t4][qd][ncl][0];
            const h8 wp = *(const h8*)&sW1[bkt][1][t4][qd][ncl][0];
            cb = __builtin_amdgcn_mfma_f32_16x16x32_f16(xa, wa, cb, 0, 0, 0);
            cp = __builtin_amdgcn_mfma_f32_16x16x32_f16(xp, wp, cp, 0, 0, 0);
        }

        // ---- epilogue 1: l1c pairs -> per-wave scratch; col 8 -> acc dots ----
        if (col < 8) {
            #pragma unroll
            for (int r = 0; r < 4; ++r) {
                const int row = qd * 4 + r;
                float v = cb[r];
                *(h2*)(lb + row * 80 + col * 4) =
                    pk2(fminf(v * v * (255.0f / 256.0f), 1.0f),
                        fminf(fmaxf(v, 0.0f), 1.0f));
                v = cp[r];
                *(h2*)(lb + row * 80 + 32 + col * 4) =
                    pk2(fminf(v * v * (255.0f / 256.0f), 1.0f),
                        fminf(fmaxf(v, 0.0f), 1.0f));
            }
        } else if (col == 8) {
            #pragma unroll
            for (int r = 0; r < 4; ++r) {
                const int row = qd * 4 + r;
                *(float*)(lb + row * 80 + 64) = cb[r];   // accA
                *(float*)(lb + row * 80 + 68) = cp[r];   // accP
            }
        }

        // ---- stage 2: L2 (K=32) as 4 N-tiles of 16, seeded with b2 ----
        const h8 a2 = *(const h8*)(lb + col * 80 + qd * 16);
        const float s0 = sB2[bkt][col];
        const float s1 = sB2[bkt][16 + col];
        const float s2 = sB2[bkt][32 + col];
        const float s3 = sB2[bkt][48 + col];
        f4 c20 = {s0, s0, s0, s0};
        f4 c21 = {s1, s1, s1, s1};
        f4 c22 = {s2, s2, s2, s2};
        f4 c23 = {s3, s3, s3, s3};
        c20 = __builtin_amdgcn_mfma_f32_16x16x32_f16(a2, *(const h8*)&sW2[bkt][0][qd][col][0], c20, 0, 0, 0);
        c21 = __builtin_amdgcn_mfma_f32_16x16x32_f16(a2, *(const h8*)&sW2[bkt][1][qd][col][0], c21, 0, 0, 0);
        c22 = __builtin_amdgcn_mfma_f32_16x16x32_f16(a2, *(const h8*)&sW2[bkt][2][qd][col][0], c22, 0, 0, 0);
        c23 = __builtin_amdgcn_mfma_f32_16x16x32_f16(a2, *(const h8*)&sW2[bkt][3][qd][col][0], c23, 0, 0, 0);

        // ---- epilogue 2: activation + Wout[0:64) dot + 16-lane reduce ----
        const float wo0 = sWo0[bkt][col];
        const float wo1 = sWo0[bkt][16 + col];
        const float wo2 = sWo0[bkt][32 + col];
        const float wo3 = sWo0[bkt][48 + col];
        float p0 = actv(c20[0]) * wo0 + actv(c21[0]) * wo1 + actv(c22[0]) * wo2 + actv(c23[0]) * wo3;
        float p1 = actv(c20[1]) * wo0 + actv(c21[1]) * wo1 + actv(c22[1]) * wo2 + actv(c23[1]) * wo3;
        float p2 = actv(c20[2]) * wo0 + actv(c21[2]) * wo1 + actv(c22[2]) * wo2 + actv(c23[2]) * wo3;
        float p3 = actv(c20[3]) * wo0 + actv(c21[3]) * wo1 + actv(c22[3]) * wo2 + actv(c23[3]) * wo3;
        #pragma unroll
        for (int m = 1; m < 16; m <<= 1) {
            p0 += __shfl_xor(p0, m, 64);
            p1 += __shfl_xor(p1, m, 64);
            p2 += __shfl_xor(p2, m, 64);
            p3 += __shfl_xor(p3, m, 64);
        }

        if (col == 0) {
            const float bo = sBout[bkt];
            if (sl0 >= 0)
                out[gbase + sl0] = bo + *(const float*)(lb + (qd * 4 + 0) * 80 + 64)
                                      + *(const float*)(lb + (qd * 4 + 0) * 80 + 68) + p0;
            if (sl1 >= 0)
                out[gbase + sl1] = bo + *(const float*)(lb + (qd * 4 + 1) * 80 + 64)
                                      + *(const float*)(lb + (qd * 4 + 1) * 80 + 68) + p1;
            if (sl2 >= 0)
                out[gbase + sl2] = bo + *(const float*)(lb + (qd * 4 + 2) * 80 + 64)
                                      + *(const float*)(lb + (qd * 4 + 2) * 80 + 68) + p2;
            if (sl3 >= 0)
                out[gbase + sl3] = bo + *(const float*)(lb + (qd * 4 + 3) * 80 + 64)
                                      + *(const float*)(lb + (qd * 4 + 3) * 80 + 68) + p3;
        }
    }
}

extern "C" void kernel_launch(void* const* d_in, const int* in_sizes, int n_in,
                              void* d_out, int out_size, void* d_ws, size_t ws_size,
                              hipStream_t stream) {
    const float* x_base   = (const float*)d_in[0];
    const float* x_pa     = (const float*)d_in[1];
    const float* mobility = (const float*)d_in[2];
    const int*   ply      = (const int*)d_in[3];
    const float* W1b      = (const float*)d_in[4];
    const float* b1b      = (const float*)d_in[5];
    const float* W1pa     = (const float*)d_in[6];
    const float* b1pa     = (const float*)d_in[7];
    const float* W2       = (const float*)d_in[8];
    const float* b2       = (const float*)d_in[9];
    const float* Wout     = (const float*)d_in[10];
    const float* bout     = (const float*)d_in[11];
    float* out = (float*)d_out;

    const int B = in_sizes[3];              // 262144 (multiple of 1024)
    const int blocks = B >> 10;             // 256
    layerstacks_mfma<<<blocks, 1024, 0, stream>>>(
        x_base, x_pa, mobility, ply, W1b, b1b, W1pa, b1pa, W2, b2, Wout, bout, out);
}

// Round 9
// 61.115 us; speedup vs baseline: 6.6325x; 1.0355x over previous
//
#include <hip/hip_runtime.h>

// LayerStacks round 9: R8 MFMA structure + batched x loads.
// Change vs R8: stage-1 issues ALL 16 global float4 loads (8 x_base + 8 x_pa)
// as named registers BEFORE any pack/MFMA, so the wave keeps 16 loads in
// flight instead of ~2 (R8 counters: all pipes <15% busy => load-latency
// bound). Weight fragments (LDS) are also hoisted. Everything else identical.

#define NB 6

typedef _Float16 h2 __attribute__((ext_vector_type(2)));
typedef _Float16 h8 __attribute__((ext_vector_type(8)));
typedef float f4 __attribute__((ext_vector_type(4)));

__device__ __forceinline__ h2 pk2(float x, float y) {
    return __builtin_bit_cast(h2, __builtin_amdgcn_cvt_pkrtz(x, y));
}

__device__ __forceinline__ h8 pack8(const float4 a, const float4 b) {
    h2 p0 = pk2(a.x, a.y), p1 = pk2(a.z, a.w);
    h2 p2 = pk2(b.x, b.y), p3 = pk2(b.z, b.w);
    h8 r;
    r[0] = p0[0]; r[1] = p0[1]; r[2] = p1[0]; r[3] = p1[1];
    r[4] = p2[0]; r[5] = p2[1]; r[6] = p3[0]; r[7] = p3[1];
    return r;
}

__device__ __forceinline__ float actv(float v) {
    float u = fminf(fmaxf(v, 0.0f), 1.0f);
    return u * u * (255.0f / 256.0f);
}

__global__ __launch_bounds__(1024, 1)
void layerstacks_mfma(const float* __restrict__ x_base,
                      const float* __restrict__ x_pa,
                      const float* __restrict__ mobility,
                      const int*   __restrict__ ply,
                      const float* __restrict__ W1b,
                      const float* __restrict__ b1b,
                      const float* __restrict__ W1pa,
                      const float* __restrict__ b1pa,
                      const float* __restrict__ W2,
                      const float* __restrict__ b2,
                      const float* __restrict__ Wout,
                      const float* __restrict__ bout,
                      float* __restrict__ out)
{
    __shared__ __align__(16) _Float16 sW1[NB][2][4][4][9][8];
    __shared__ __align__(16) _Float16 sW2[NB][4][4][16][8];
    __shared__ float sWo0[NB][64];
    __shared__ float sB2[NB][64];
    __shared__ float sB1[NB][4][8];
    __shared__ float sBout[NB];
    __shared__ float sMob[1024];
    __shared__ int   sList[1120];
    __shared__ __align__(16) char sL1[16 * 1280];
    __shared__ int sCnt[8], sCur[8], sTb[72];
    __shared__ int sNt;

    const int tid   = threadIdx.x;
    const int lane  = tid & 63;
    const int w     = tid >> 6;
    const int gbase = blockIdx.x << 10;

    // ---------------- phase 0: staging --------------------------------------
    if (tid < 8) { sCnt[tid] = 0; }

    for (int e = tid; e < NB * 2 * 4 * 4 * 9 * 8; e += 1024) {
        int i = e & 7;
        int rest = e >> 3;
        int n = rest % 9;   rest /= 9;
        int kb = rest & 3;  rest >>= 2;
        int t = rest & 3;   rest >>= 2;
        int st = rest & 1;
        int b = rest >> 1;
        int k = t * 32 + kb * 8 + i;
        float v;
        if (n < 8) {
            const float* Wx = st ? W1pa : W1b;
            v = Wx[b * 1032 + n * 129 + k];
        } else {
            v = st ? Wout[b * 320 + 192 + k] : Wout[b * 320 + 64 + k];
        }
        sW1[b][st][t][kb][n][i] = (_Float16)v;
    }
    for (int e = tid; e < NB * 4 * 4 * 16 * 8; e += 1024) {
        int i = e & 7;
        int j = (e >> 3) & 15;
        int kb = (e >> 7) & 3;
        int T = (e >> 9) & 3;
        int b = e >> 11;
        int n = T * 16 + j;
        int k = kb * 8 + i;
        int u = k >> 1;
        int colw = (k & 1) ? (16 + u) : u;
        sW2[b][T][kb][j][i] = (_Float16)W2[b * 2048 + n * 32 + colw];
    }
    for (int e = tid; e < NB * 64; e += 1024) {
        int b = e >> 6, n = e & 63;
        sWo0[b][n] = Wout[b * 320 + n];
        sB2[b][n]  = b2[e];
    }
    if (tid < NB * 4 * 8) {
        int n = tid & 7, which = (tid >> 3) & 3, b = tid >> 5;
        float v;
        if (which == 0)      v = b1b[b * 8 + n];
        else if (which == 1) v = b1pa[b * 8 + n];
        else if (which == 2) v = W1b [b * 1032 + n * 129 + 128];
        else                 v = W1pa[b * 1032 + n * 129 + 128];
        sB1[b][which][n] = v;
    }
    if (tid < NB) sBout[tid] = bout[tid];
    sMob[tid] = fminf(mobility[gbase + tid] * (7.0f / 255.0f), 1.0f);
    for (int e = tid; e < 1120; e += 1024) sList[e] = -1;

    const int bb = ply[gbase + tid] / 10;
    __syncthreads();

    // ---------------- phase 1: ballot-aggregated counts ---------------------
    #pragma unroll
    for (int b = 0; b < NB; ++b) {
        unsigned long long mk = __ballot(bb == b);
        if (bb == b) {
            int lead = __ffsll((long long)mk) - 1;
            if (lane == lead) atomicAdd(&sCnt[b], __popcll(mk));
        }
    }
    __syncthreads();

    // ---------------- phase 2: offsets + tile->bucket map -------------------
    if (tid == 0) {
        int off = 0, tt = 0;
        for (int b = 0; b < NB; ++b) {
            sCur[b] = off;
            int ntl = (sCnt[b] + 15) >> 4;
            for (int q = 0; q < ntl; ++q) sTb[tt++] = b;
            off += ntl << 4;
        }
        sNt = tt;
    }
    __syncthreads();

    // ---------------- phase 3: scatter local indices ------------------------
    #pragma unroll
    for (int b = 0; b < NB; ++b) {
        unsigned long long mk = __ballot(bb == b);
        if (bb == b) {
            int lead = __ffsll((long long)mk) - 1;
            int pfx = __popcll(mk & ((1ull << lane) - 1ull));
            int base = 0;
            if (lane == lead) base = atomicAdd(&sCur[b], __popcll(mk));
            base = __shfl(base, lead);
            sList[base + pfx] = tid;
        }
    }
    __syncthreads();

    // ---------------- main: per-wave MFMA tiles -----------------------------
    const int ntiles = sNt;
    const int col = lane & 15;
    const int qd  = lane >> 4;
    char* lb = sL1 + w * 1280;

    for (int tl = w; tl < ntiles; tl += 16) {
        const int bkt = sTb[tl];
        const int t16 = tl << 4;

        const int sl0 = sList[t16 + qd * 4 + 0];
        const int sl1 = sList[t16 + qd * 4 + 1];
        const int sl2 = sList[t16 + qd * 4 + 2];
        const int sl3 = sList[t16 + qd * 4 + 3];
        int sA = sList[t16 + col];
        if (sA < 0) sA = sList[t16];

        // ---- batched x loads: 16 independent float4s, all in flight --------
        const float* xbrow = x_base + (size_t)(gbase + sA) * 128 + qd * 8;
        const float* xprow = x_pa   + (size_t)(gbase + sA) * 128 + qd * 8;
        const float4 b00 = *(const float4*)(xbrow + 0);
        const float4 b01 = *(const float4*)(xbrow + 4);
        const float4 b10 = *(const float4*)(xbrow + 32);
        const float4 b11 = *(const float4*)(xbrow + 36);
        const float4 b20 = *(const float4*)(xbrow + 64);
        const float4 b21 = *(const float4*)(xbrow + 68);
        const float4 b30 = *(const float4*)(xbrow + 96);
        const float4 b31 = *(const float4*)(xbrow + 100);
        const float4 q00 = *(const float4*)(xprow + 0);
        const float4 q01 = *(const float4*)(xprow + 4);
        const float4 q10 = *(const float4*)(xprow + 32);
        const float4 q11 = *(const float4*)(xprow + 36);
        const float4 q20 = *(const float4*)(xprow + 64);
        const float4 q21 = *(const float4*)(xprow + 68);
        const float4 q30 = *(const float4*)(xprow + 96);
        const float4 q31 = *(const float4*)(xprow + 100);

        const float mob0 = (sl0 >= 0) ? sMob[sl0 & 1023] : 0.0f;
        const float mob1 = (sl1 >= 0) ? sMob[sl1 & 1023] : 0.0f;
        const float mob2 = (sl2 >= 0) ? sMob[sl2 & 1023] : 0.0f;
        const float mob3 = (sl3 >= 0) ? sMob[sl3 & 1023] : 0.0f;

        const int c7 = col & 7;
        const bool a8 = (col < 8);
        const int ncl = a8 ? col : 8;

        // ---- weight fragments (LDS), hoisted -------------------------------
        const h8 wa0 = *(const h8*)&sW1[bkt][0][0][qd][ncl][0];
        const h8 wa1 = *(const h8*)&sW1[bkt][0][1][qd][ncl][0];
        const h8 wa2 = *(const h8*)&sW1[bkt][0][2][qd][ncl][0];
        const h8 wa3 = *(const h8*)&sW1[bkt][0][3][qd][ncl][0];
        const h8 wp0 = *(const h8*)&sW1[bkt][1][0][qd][ncl][0];
        const h8 wp1 = *(const h8*)&sW1[bkt][1][1][qd][ncl][0];
        const h8 wp2 = *(const h8*)&sW1[bkt][1][2][qd][ncl][0];
        const h8 wp3 = *(const h8*)&sW1[bkt][1][3][qd][ncl][0];

        // ---- stage 1 seeds -------------------------------------------------
        const float bb1 = sB1[bkt][0][c7], bp1 = sB1[bkt][1][c7];
        const float mwb = sB1[bkt][2][c7], mwp = sB1[bkt][3][c7];
        f4 cb, cp;
        cb[0] = a8 ? bb1 + mwb * mob0 : 0.0f;
        cb[1] = a8 ? bb1 + mwb * mob1 : 0.0f;
        cb[2] = a8 ? bb1 + mwb * mob2 : 0.0f;
        cb[3] = a8 ? bb1 + mwb * mob3 : 0.0f;
        cp[0] = a8 ? bp1 + mwp * mob0 : 0.0f;
        cp[1] = a8 ? bp1 + mwp * mob1 : 0.0f;
        cp[2] = a8 ? bp1 + mwp * mob2 : 0.0f;
        cp[3] = a8 ? bp1 + mwp * mob3 : 0.0f;

        // ---- stage 1: K=128 in 4 MFMA steps per stream ---------------------
        cb = __builtin_amdgcn_mfma_f32_16x16x32_f16(pack8(b00, b01), wa0, cb, 0, 0, 0);
        cp = __builtin_amdgcn_mfma_f32_16x16x32_f16(pack8(q00, q01), wp0, cp, 0, 0, 0);
        cb = __builtin_amdgcn_mfma_f32_16x16x32_f16(pack8(b10, b11), wa1, cb, 0, 0, 0);
        cp = __builtin_amdgcn_mfma_f32_16x16x32_f16(pack8(q10, q11), wp1, cp, 0, 0, 0);
        cb = __builtin_amdgcn_mfma_f32_16x16x32_f16(pack8(b20, b21), wa2, cb, 0, 0, 0);
        cp = __builtin_amdgcn_mfma_f32_16x16x32_f16(pack8(q20, q21), wp2, cp, 0, 0, 0);
        cb = __builtin_amdgcn_mfma_f32_16x16x32_f16(pack8(b30, b31), wa3, cb, 0, 0, 0);
        cp = __builtin_amdgcn_mfma_f32_16x16x32_f16(pack8(q30, q31), wp3, cp, 0, 0, 0);

        // ---- epilogue 1: l1c pairs -> per-wave scratch ---------------------
        if (col < 8) {
            #pragma unroll
            for (int r = 0; r < 4; ++r) {
                const int row = qd * 4 + r;
                float v = cb[r];
                *(h2*)(lb + row * 80 + col * 4) =
                    pk2(fminf(v * v * (255.0f / 256.0f), 1.0f),
                        fminf(fmaxf(v, 0.0f), 1.0f));
                v = cp[r];
                *(h2*)(lb + row * 80 + 32 + col * 4) =
                    pk2(fminf(v * v * (255.0f / 256.0f), 1.0f),
                        fminf(fmaxf(v, 0.0f), 1.0f));
            }
        } else if (col == 8) {
            #pragma unroll
            for (int r = 0; r < 4; ++r) {
                const int row = qd * 4 + r;
                *(float*)(lb + row * 80 + 64) = cb[r];
                *(float*)(lb + row * 80 + 68) = cp[r];
            }
        }

        // ---- stage 2: L2 (K=32) as 4 N-tiles of 16 -------------------------
        const h8 a2 = *(const h8*)(lb + col * 80 + qd * 16);
        const float s0 = sB2[bkt][col];
        const float s1 = sB2[bkt][16 + col];
        const float s2 = sB2[bkt][32 + col];
        const float s3 = sB2[bkt][48 + col];
        f4 c20 = {s0, s0, s0, s0};
        f4 c21 = {s1, s1, s1, s1};
        f4 c22 = {s2, s2, s2, s2};
        f4 c23 = {s3, s3, s3, s3};
        c20 = __builtin_amdgcn_mfma_f32_16x16x32_f16(a2, *(const h8*)&sW2[bkt][0][qd][col][0], c20, 0, 0, 0);
        c21 = __builtin_amdgcn_mfma_f32_16x16x32_f16(a2, *(const h8*)&sW2[bkt][1][qd][col][0], c21, 0, 0, 0);
        c22 = __builtin_amdgcn_mfma_f32_16x16x32_f16(a2, *(const h8*)&sW2[bkt][2][qd][col][0], c22, 0, 0, 0);
        c23 = __builtin_amdgcn_mfma_f32_16x16x32_f16(a2, *(const h8*)&sW2[bkt][3][qd][col][0], c23, 0, 0, 0);

        // ---- epilogue 2: activation + Wout[0:64) dot + reduce --------------
        const float wo0 = sWo0[bkt][col];
        const float wo1 = sWo0[bkt][16 + col];
        const float wo2 = sWo0[bkt][32 + col];
        const float wo3 = sWo0[bkt][48 + col];
        float p0 = actv(c20[0]) * wo0 + actv(c21[0]) * wo1 + actv(c22[0]) * wo2 + actv(c23[0]) * wo3;
        float p1 = actv(c20[1]) * wo0 + actv(c21[1]) * wo1 + actv(c22[1]) * wo2 + actv(c23[1]) * wo3;
        float p2 = actv(c20[2]) * wo0 + actv(c21[2]) * wo1 + actv(c22[2]) * wo2 + actv(c23[2]) * wo3;
        float p3 = actv(c20[3]) * wo0 + actv(c21[3]) * wo1 + actv(c22[3]) * wo2 + actv(c23[3]) * wo3;
        #pragma unroll
        for (int m = 1; m < 16; m <<= 1) {
            p0 += __shfl_xor(p0, m, 64);
            p1 += __shfl_xor(p1, m, 64);
            p2 += __shfl_xor(p2, m, 64);
            p3 += __shfl_xor(p3, m, 64);
        }

        if (col == 0) {
            const float bo = sBout[bkt];
            if (sl0 >= 0)
                out[gbase + sl0] = bo + *(const float*)(lb + (qd * 4 + 0) * 80 + 64)
                                      + *(const float*)(lb + (qd * 4 + 0) * 80 + 68) + p0;
            if (sl1 >= 0)
                out[gbase + sl1] = bo + *(const float*)(lb + (qd * 4 + 1) * 80 + 64)
                                      + *(const float*)(lb + (qd * 4 + 1) * 80 + 68) + p1;
            if (sl2 >= 0)
                out[gbase + sl2] = bo + *(const float*)(lb + (qd * 4 + 2) * 80 + 64)
                                      + *(const float*)(lb + (qd * 4 + 2) * 80 + 68) + p2;
            if (sl3 >= 0)
                out[gbase + sl3] = bo + *(const float*)(lb + (qd * 4 + 3) * 80 + 64)
                                      + *(const float*)(lb + (qd * 4 + 3) * 80 + 68) + p3;
        }
    }
}

extern "C" void kernel_launch(void* const* d_in, const int* in_sizes, int n_in,
                              void* d_out, int out_size, void* d_ws, size_t ws_size,
                              hipStream_t stream) {
    const float* x_base   = (const float*)d_in[0];
    const float* x_pa     = (const float*)d_in[1];
    const float* mobility = (const float*)d_in[2];
    const int*   ply      = (const int*)d_in[3];
    const float* W1b      = (const float*)d_in[4];
    const float* b1b      = (const float*)d_in[5];
    const float* W1pa     = (const float*)d_in[6];
    const float* b1pa     = (const float*)d_in[7];
    const float* W2       = (const float*)d_in[8];
    const float* b2       = (const float*)d_in[9];
    const float* Wout     = (const float*)d_in[10];
    const float* bout     = (const float*)d_in[11];
    float* out = (float*)d_out;

    const int B = in_sizes[3];              // 262144 (multiple of 1024)
    const int blocks = B >> 10;             // 256
    layerstacks_mfma<<<blocks, 1024, 0, stream>>>(
        x_base, x_pa, mobility, ply, W1b, b1b, W1pa, b1pa, W2, b2, Wout, bout, out);
}

// Round 10
// 60.786 us; speedup vs baseline: 6.6685x; 1.0054x over previous
//
#include <hip/hip_runtime.h>

// LayerStacks round 10: R9 MFMA structure re-blocked for occupancy.
// 512-thread blocks covering 512 samples => LDS ~69 KB < 80 KB => 2 blocks/CU
// => 8 waves/SIMD (was 4). Counters showed pure latency-bound (all pipes <15%),
// so doubled TLP is the direct lever. Logic otherwise identical to R9.

#define NB 6
#define BT 512                  // block threads == samples per block
#define NW (BT / 64)            // waves per block = 8

typedef _Float16 h2 __attribute__((ext_vector_type(2)));
typedef _Float16 h8 __attribute__((ext_vector_type(8)));
typedef float f4 __attribute__((ext_vector_type(4)));

__device__ __forceinline__ h2 pk2(float x, float y) {
    return __builtin_bit_cast(h2, __builtin_amdgcn_cvt_pkrtz(x, y));
}

__device__ __forceinline__ h8 pack8(const float4 a, const float4 b) {
    h2 p0 = pk2(a.x, a.y), p1 = pk2(a.z, a.w);
    h2 p2 = pk2(b.x, b.y), p3 = pk2(b.z, b.w);
    h8 r;
    r[0] = p0[0]; r[1] = p0[1]; r[2] = p1[0]; r[3] = p1[1];
    r[4] = p2[0]; r[5] = p2[1]; r[6] = p3[0]; r[7] = p3[1];
    return r;
}

__device__ __forceinline__ float actv(float v) {
    float u = fminf(fmaxf(v, 0.0f), 1.0f);
    return u * u * (255.0f / 256.0f);
}

__global__ __launch_bounds__(BT, 4)
void layerstacks_mfma(const float* __restrict__ x_base,
                      const float* __restrict__ x_pa,
                      const float* __restrict__ mobility,
                      const int*   __restrict__ ply,
                      const float* __restrict__ W1b,
                      const float* __restrict__ b1b,
                      const float* __restrict__ W1pa,
                      const float* __restrict__ b1pa,
                      const float* __restrict__ W2,
                      const float* __restrict__ b2,
                      const float* __restrict__ Wout,
                      const float* __restrict__ bout,
                      float* __restrict__ out)
{
    __shared__ __align__(16) _Float16 sW1[NB][2][4][4][9][8];   // 27.6 KB
    __shared__ __align__(16) _Float16 sW2[NB][4][4][16][8];     // 24.6 KB
    __shared__ float sWo0[NB][64];
    __shared__ float sB2[NB][64];
    __shared__ float sB1[NB][4][8];
    __shared__ float sBout[NB];
    __shared__ float sMob[BT];
    __shared__ int   sList[BT + NB * 16];
    __shared__ __align__(16) char sL1[NW * 1280];
    __shared__ int sCnt[8], sCur[8], sTb[40];
    __shared__ int sNt;

    const int tid   = threadIdx.x;
    const int lane  = tid & 63;
    const int w     = tid >> 6;
    const int gbase = blockIdx.x * BT;

    // ---------------- phase 0: staging --------------------------------------
    if (tid < 8) { sCnt[tid] = 0; }

    for (int e = tid; e < NB * 2 * 4 * 4 * 9 * 8; e += BT) {
        int i = e & 7;
        int rest = e >> 3;
        int n = rest % 9;   rest /= 9;
        int kb = rest & 3;  rest >>= 2;
        int t = rest & 3;   rest >>= 2;
        int st = rest & 1;
        int b = rest >> 1;
        int k = t * 32 + kb * 8 + i;
        float v;
        if (n < 8) {
            const float* Wx = st ? W1pa : W1b;
            v = Wx[b * 1032 + n * 129 + k];
        } else {
            v = st ? Wout[b * 320 + 192 + k] : Wout[b * 320 + 64 + k];
        }
        sW1[b][st][t][kb][n][i] = (_Float16)v;
    }
    for (int e = tid; e < NB * 4 * 4 * 16 * 8; e += BT) {
        int i = e & 7;
        int j = (e >> 3) & 15;
        int kb = (e >> 7) & 3;
        int T = (e >> 9) & 3;
        int b = e >> 11;
        int n = T * 16 + j;
        int k = kb * 8 + i;
        int u = k >> 1;
        int colw = (k & 1) ? (16 + u) : u;
        sW2[b][T][kb][j][i] = (_Float16)W2[b * 2048 + n * 32 + colw];
    }
    for (int e = tid; e < NB * 64; e += BT) {
        int b = e >> 6, n = e & 63;
        sWo0[b][n] = Wout[b * 320 + n];
        sB2[b][n]  = b2[e];
    }
    if (tid < NB * 4 * 8) {
        int n = tid & 7, which = (tid >> 3) & 3, b = tid >> 5;
        float v;
        if (which == 0)      v = b1b[b * 8 + n];
        else if (which == 1) v = b1pa[b * 8 + n];
        else if (which == 2) v = W1b [b * 1032 + n * 129 + 128];
        else                 v = W1pa[b * 1032 + n * 129 + 128];
        sB1[b][which][n] = v;
    }
    if (tid < NB) sBout[tid] = bout[tid];
    sMob[tid] = fminf(mobility[gbase + tid] * (7.0f / 255.0f), 1.0f);
    for (int e = tid; e < BT + NB * 16; e += BT) sList[e] = -1;

    const int bb = ply[gbase + tid] / 10;
    __syncthreads();

    // ---------------- phase 1: ballot-aggregated counts ---------------------
    #pragma unroll
    for (int b = 0; b < NB; ++b) {
        unsigned long long mk = __ballot(bb == b);
        if (bb == b) {
            int lead = __ffsll((long long)mk) - 1;
            if (lane == lead) atomicAdd(&sCnt[b], __popcll(mk));
        }
    }
    __syncthreads();

    // ---------------- phase 2: offsets + tile->bucket map -------------------
    if (tid == 0) {
        int off = 0, tt = 0;
        for (int b = 0; b < NB; ++b) {
            sCur[b] = off;
            int ntl = (sCnt[b] + 15) >> 4;
            for (int q = 0; q < ntl; ++q) sTb[tt++] = b;
            off += ntl << 4;
        }
        sNt = tt;
    }
    __syncthreads();

    // ---------------- phase 3: scatter local indices ------------------------
    #pragma unroll
    for (int b = 0; b < NB; ++b) {
        unsigned long long mk = __ballot(bb == b);
        if (bb == b) {
            int lead = __ffsll((long long)mk) - 1;
            int pfx = __popcll(mk & ((1ull << lane) - 1ull));
            int base = 0;
            if (lane == lead) base = atomicAdd(&sCur[b], __popcll(mk));
            base = __shfl(base, lead);
            sList[base + pfx] = tid;
        }
    }
    __syncthreads();

    // ---------------- main: per-wave MFMA tiles -----------------------------
    const int ntiles = sNt;
    const int col = lane & 15;
    const int qd  = lane >> 4;
    char* lb = sL1 + w * 1280;

    for (int tl = w; tl < ntiles; tl += NW) {
        const int bkt = sTb[tl];
        const int t16 = tl << 4;

        const int sl0 = sList[t16 + qd * 4 + 0];
        const int sl1 = sList[t16 + qd * 4 + 1];
        const int sl2 = sList[t16 + qd * 4 + 2];
        const int sl3 = sList[t16 + qd * 4 + 3];
        int sA = sList[t16 + col];
        if (sA < 0) sA = sList[t16];

        const float* xbrow = x_base + (size_t)(gbase + sA) * 128 + qd * 8;
        const float* xprow = x_pa   + (size_t)(gbase + sA) * 128 + qd * 8;
        const float4 b00 = *(const float4*)(xbrow + 0);
        const float4 b01 = *(const float4*)(xbrow + 4);
        const float4 b10 = *(const float4*)(xbrow + 32);
        const float4 b11 = *(const float4*)(xbrow + 36);
        const float4 b20 = *(const float4*)(xbrow + 64);
        const float4 b21 = *(const float4*)(xbrow + 68);
        const float4 b30 = *(const float4*)(xbrow + 96);
        const float4 b31 = *(const float4*)(xbrow + 100);
        const float4 q00 = *(const float4*)(xprow + 0);
        const float4 q01 = *(const float4*)(xprow + 4);
        const float4 q10 = *(const float4*)(xprow + 32);
        const float4 q11 = *(const float4*)(xprow + 36);
        const float4 q20 = *(const float4*)(xprow + 64);
        const float4 q21 = *(const float4*)(xprow + 68);
        const float4 q30 = *(const float4*)(xprow + 96);
        const float4 q31 = *(const float4*)(xprow + 100);

        const float mob0 = (sl0 >= 0) ? sMob[sl0] : 0.0f;
        const float mob1 = (sl1 >= 0) ? sMob[sl1] : 0.0f;
        const float mob2 = (sl2 >= 0) ? sMob[sl2] : 0.0f;
        const float mob3 = (sl3 >= 0) ? sMob[sl3] : 0.0f;

        const int c7 = col & 7;
        const bool a8 = (col < 8);
        const int ncl = a8 ? col : 8;

        const h8 wa0 = *(const h8*)&sW1[bkt][0][0][qd][ncl][0];
        const h8 wa1 = *(const h8*)&sW1[bkt][0][1][qd][ncl][0];
        const h8 wa2 = *(const h8*)&sW1[bkt][0][2][qd][ncl][0];
        const h8 wa3 = *(const h8*)&sW1[bkt][0][3][qd][ncl][0];
        const h8 wp0 = *(const h8*)&sW1[bkt][1][0][qd][ncl][0];
        const h8 wp1 = *(const h8*)&sW1[bkt][1][1][qd][ncl][0];
        const h8 wp2 = *(const h8*)&sW1[bkt][1][2][qd][ncl][0];
        const h8 wp3 = *(const h8*)&sW1[bkt][1][3][qd][ncl][0];

        const float bb1 = sB1[bkt][0][c7], bp1 = sB1[bkt][1][c7];
        const float mwb = sB1[bkt][2][c7], mwp = sB1[bkt][3][c7];
        f4 cb, cp;
        cb[0] = a8 ? bb1 + mwb * mob0 : 0.0f;
        cb[1] = a8 ? bb1 + mwb * mob1 : 0.0f;
        cb[2] = a8 ? bb1 + mwb * mob2 : 0.0f;
        cb[3] = a8 ? bb1 + mwb * mob3 : 0.0f;
        cp[0] = a8 ? bp1 + mwp * mob0 : 0.0f;
        cp[1] = a8 ? bp1 + mwp * mob1 : 0.0f;
        cp[2] = a8 ? bp1 + mwp * mob2 : 0.0f;
        cp[3] = a8 ? bp1 + mwp * mob3 : 0.0f;

        cb = __builtin_amdgcn_mfma_f32_16x16x32_f16(pack8(b00, b01), wa0, cb, 0, 0, 0);
        cp = __builtin_amdgcn_mfma_f32_16x16x32_f16(pack8(q00, q01), wp0, cp, 0, 0, 0);
        cb = __builtin_amdgcn_mfma_f32_16x16x32_f16(pack8(b10, b11), wa1, cb, 0, 0, 0);
        cp = __builtin_amdgcn_mfma_f32_16x16x32_f16(pack8(q10, q11), wp1, cp, 0, 0, 0);
        cb = __builtin_amdgcn_mfma_f32_16x16x32_f16(pack8(b20, b21), wa2, cb, 0, 0, 0);
        cp = __builtin_amdgcn_mfma_f32_16x16x32_f16(pack8(q20, q21), wp2, cp, 0, 0, 0);
        cb = __builtin_amdgcn_mfma_f32_16x16x32_f16(pack8(b30, b31), wa3, cb, 0, 0, 0);
        cp = __builtin_amdgcn_mfma_f32_16x16x32_f16(pack8(q30, q31), wp3, cp, 0, 0, 0);

        if (col < 8) {
            #pragma unroll
            for (int r = 0; r < 4; ++r) {
                const int row = qd * 4 + r;
                float v = cb[r];
                *(h2*)(lb + row * 80 + col * 4) =
                    pk2(fminf(v * v * (255.0f / 256.0f), 1.0f),
                        fminf(fmaxf(v, 0.0f), 1.0f));
                v = cp[r];
                *(h2*)(lb + row * 80 + 32 + col * 4) =
                    pk2(fminf(v * v * (255.0f / 256.0f), 1.0f),
                        fminf(fmaxf(v, 0.0f), 1.0f));
            }
        } else if (col == 8) {
            #pragma unroll
            for (int r = 0; r < 4; ++r) {
                const int row = qd * 4 + r;
                *(float*)(lb + row * 80 + 64) = cb[r];
                *(float*)(lb + row * 80 + 68) = cp[r];
            }
        }

        const h8 a2 = *(const h8*)(lb + col * 80 + qd * 16);
        const float s0 = sB2[bkt][col];
        const float s1 = sB2[bkt][16 + col];
        const float s2 = sB2[bkt][32 + col];
        const float s3 = sB2[bkt][48 + col];
        f4 c20 = {s0, s0, s0, s0};
        f4 c21 = {s1, s1, s1, s1};
        f4 c22 = {s2, s2, s2, s2};
        f4 c23 = {s3, s3, s3, s3};
        c20 = __builtin_amdgcn_mfma_f32_16x16x32_f16(a2, *(const h8*)&sW2[bkt][0][qd][col][0], c20, 0, 0, 0);
        c21 = __builtin_amdgcn_mfma_f32_16x16x32_f16(a2, *(const h8*)&sW2[bkt][1][qd][col][0], c21, 0, 0, 0);
        c22 = __builtin_amdgcn_mfma_f32_16x16x32_f16(a2, *(const h8*)&sW2[bkt][2][qd][col][0], c22, 0, 0, 0);
        c23 = __builtin_amdgcn_mfma_f32_16x16x32_f16(a2, *(const h8*)&sW2[bkt][3][qd][col][0], c23, 0, 0, 0);

        const float wo0 = sWo0[bkt][col];
        const float wo1 = sWo0[bkt][16 + col];
        const float wo2 = sWo0[bkt][32 + col];
        const float wo3 = sWo0[bkt][48 + col];
        float p0 = actv(c20[0]) * wo0 + actv(c21[0]) * wo1 + actv(c22[0]) * wo2 + actv(c23[0]) * wo3;
        float p1 = actv(c20[1]) * wo0 + actv(c21[1]) * wo1 + actv(c22[1]) * wo2 + actv(c23[1]) * wo3;
        float p2 = actv(c20[2]) * wo0 + actv(c21[2]) * wo1 + actv(c22[2]) * wo2 + actv(c23[2]) * wo3;
        float p3 = actv(c20[3]) * wo0 + actv(c21[3]) * wo1 + actv(c22[3]) * wo2 + actv(c23[3]) * wo3;
        #pragma unroll
        for (int m = 1; m < 16; m <<= 1) {
            p0 += __shfl_xor(p0, m, 64);
            p1 += __shfl_xor(p1, m, 64);
            p2 += __shfl_xor(p2, m, 64);
            p3 += __shfl_xor(p3, m, 64);
        }

        if (col == 0) {
            const float bo = sBout[bkt];
            if (sl0 >= 0)
                out[gbase + sl0] = bo + *(const float*)(lb + (qd * 4 + 0) * 80 + 64)
                                      + *(const float*)(lb + (qd * 4 + 0) * 80 + 68) + p0;
            if (sl1 >= 0)
                out[gbase + sl1] = bo + *(const float*)(lb + (qd * 4 + 1) * 80 + 64)
                                      + *(const float*)(lb + (qd * 4 + 1) * 80 + 68) + p1;
            if (sl2 >= 0)
                out[gbase + sl2] = bo + *(const float*)(lb + (qd * 4 + 2) * 80 + 64)
                                      + *(const float*)(lb + (qd * 4 + 2) * 80 + 68) + p2;
            if (sl3 >= 0)
                out[gbase + sl3] = bo + *(const float*)(lb + (qd * 4 + 3) * 80 + 64)
                                      + *(const float*)(lb + (qd * 4 + 3) * 80 + 68) + p3;
        }
    }
}

extern "C" void kernel_launch(void* const* d_in, const int* in_sizes, int n_in,
                              void* d_out, int out_size, void* d_ws, size_t ws_size,
                              hipStream_t stream) {
    const float* x_base   = (const float*)d_in[0];
    const float* x_pa     = (const float*)d_in[1];
    const float* mobility = (const float*)d_in[2];
    const int*   ply      = (const int*)d_in[3];
    const float* W1b      = (const float*)d_in[4];
    const float* b1b      = (const float*)d_in[5];
    const float* W1pa     = (const float*)d_in[6];
    const float* b1pa     = (const float*)d_in[7];
    const float* W2       = (const float*)d_in[8];
    const float* b2       = (const float*)d_in[9];
    const float* Wout     = (const float*)d_in[10];
    const float* bout     = (const float*)d_in[11];
    float* out = (float*)d_out;

    const int B = in_sizes[3];              // 262144 (multiple of 512)
    const int blocks = B / BT;              // 512
    layerstacks_mfma<<<blocks, BT, 0, stream>>>(
        x_base, x_pa, mobility, ply, W1b, b1b, W1pa, b1pa, W2, b2, Wout, bout, out);
}